// Round 1
// baseline (466.539 us; speedup 1.0000x reference)
//
#include <hip/hip_runtime.h>

// ---------------- problem constants ----------------
// B=4, S=2048, D=1024, H=16, HD=64; M = B*S = 8192
#define SB 4
#define SS 2048
#define SD 1024
#define SH 16
#define SHD 64
#define SM (SB * SS)   // 8192

typedef __bf16 bf16x8 __attribute__((ext_vector_type(8)));
typedef float f32x4 __attribute__((ext_vector_type(4)));

static __device__ __forceinline__ unsigned short f2bf(float x) {
    unsigned int u = __builtin_bit_cast(unsigned int, x);
    u += 0x7fffu + ((u >> 16) & 1u);   // RNE (no NaNs in this problem)
    return (unsigned short)(u >> 16);
}

typedef __attribute__((address_space(1))) void GV;
typedef __attribute__((address_space(3))) void LV;

static __device__ __forceinline__ void async16(const void* g, void* l) {
    __builtin_amdgcn_global_load_lds((GV*)g, (LV*)l, 16, 0, 0);
}

// ---------------- cast fp32 -> bf16 (vectorized) ----------------
__global__ void cast_kernel(const float* __restrict__ src,
                            unsigned short* __restrict__ dst, int n4) {
    int i = blockIdx.x * 256 + threadIdx.x;
    if (i >= n4) return;
    float4 v = reinterpret_cast<const float4*>(src)[i];
    ushort4 o;
    o.x = f2bf(v.x); o.y = f2bf(v.y); o.z = f2bf(v.z); o.w = f2bf(v.w);
    reinterpret_cast<ushort4*>(dst)[i] = o;
}

// ---------------- 128x128 GEMM mainloop (m97 structure) ----------------
// C[M,N] = A[M,K] * Bt[N,K]^T, A/Bt bf16 row-major K-contiguous.
// block = 256 threads = 4 waves (2x2), wave does 64x64 = 4x4 MFMA tiles.
__device__ __forceinline__ void gemm128_mainloop(
    const unsigned short* __restrict__ A,
    const unsigned short* __restrict__ Bt,
    int Kdim, int tileM, int tileN, int tid,
    unsigned short* As, unsigned short* Bs,
    f32x4 (&acc)[4][4]) {

    const int lane = tid & 63;
    const int quad = lane >> 4;
    const int col0 = lane & 15;
    const int wr = tid >> 7;          // wave row (0/1)
    const int wc = (tid >> 6) & 1;    // wave col (0/1)

    // staging coords: per issue, 256 threads x 16B = 64 rows of 64B
    const int srow = tid >> 2;         // 0..63
    const int schunk = (tid & 3) * 8;  // element offset in row (8 bf16 = 16B)
    const unsigned short* Ab = A + (size_t)(tileM + srow) * Kdim + schunk;
    const unsigned short* Bb = Bt + (size_t)(tileN + srow) * Kdim + schunk;
    char* AsB = (char*)As + tid * 16;
    char* BsB = (char*)Bs + tid * 16;
    const size_t rowskip = (size_t)64 * Kdim;

    for (int k0 = 0; k0 < Kdim; k0 += 32) {
        __syncthreads();   // prior reads done before overwrite
        async16(Ab + k0, AsB);
        async16(Ab + k0 + rowskip, AsB + 4096);
        async16(Bb + k0, BsB);
        async16(Bb + k0 + rowskip, BsB + 4096);
        __syncthreads();   // vmcnt drain + barrier

        bf16x8 af[4], bfr[4];
#pragma unroll
        for (int rt = 0; rt < 4; ++rt)
            af[rt] = *reinterpret_cast<const bf16x8*>(
                As + (wr * 64 + rt * 16 + col0) * 32 + quad * 8);
#pragma unroll
        for (int ct = 0; ct < 4; ++ct)
            bfr[ct] = *reinterpret_cast<const bf16x8*>(
                Bs + (wc * 64 + ct * 16 + col0) * 32 + quad * 8);
#pragma unroll
        for (int rt = 0; rt < 4; ++rt)
#pragma unroll
            for (int ct = 0; ct < 4; ++ct)
                acc[rt][ct] = __builtin_amdgcn_mfma_f32_16x16x32_bf16(
                    af[rt], bfr[ct], acc[rt][ct], 0, 0, 0);
    }
}

// ---------------- QKV projection GEMM ----------------
// A = xb [8192,1024], Bt = wqkv [3072,1024]; epilogue scatters:
//   which 0: Q [B,H,S,64]   which 1: K [B,H,S,64]   which 2: Vt [B,H,64,S]
__global__ __launch_bounds__(256) void gemm_qkv(
    const unsigned short* __restrict__ xb,
    const unsigned short* __restrict__ wqkv,
    unsigned short* __restrict__ Qd,
    unsigned short* __restrict__ Kd,
    unsigned short* __restrict__ Vtd) {

    __shared__ __align__(16) unsigned short As[128 * 32];
    __shared__ __align__(16) unsigned short Bs[128 * 32];
    const int tid = threadIdx.x;
    const int tileN = blockIdx.x * 128;
    const int tileM = blockIdx.y * 128;

    f32x4 acc[4][4];
    const f32x4 z = {0.f, 0.f, 0.f, 0.f};
#pragma unroll
    for (int i = 0; i < 4; ++i)
#pragma unroll
        for (int j = 0; j < 4; ++j) acc[i][j] = z;

    gemm128_mainloop(xb, wqkv, SD, tileM, tileN, tid, As, Bs, acc);

    const int lane = tid & 63, quad = lane >> 4, col0 = lane & 15;
    const int wr = tid >> 7, wc = (tid >> 6) & 1;

#pragma unroll
    for (int ct = 0; ct < 4; ++ct) {
        int n0 = tileN + wc * 64 + ct * 16;   // 16-col tile, uniform which/h
        int which = n0 >> 10;
        int e0 = n0 & 1023;
        int h = e0 >> 6;
        int hd = (e0 & 63) + col0;
#pragma unroll
        for (int rt = 0; rt < 4; ++rt) {
            int m0 = tileM + wr * 64 + rt * 16 + quad * 4;
            int bb = m0 >> 11;
            int s0 = m0 & 2047;
            int bh = bb * SH + h;
            if (which == 0) {
                int base = (bh * SS + s0) * SHD + hd;
#pragma unroll
                for (int r = 0; r < 4; ++r)
                    Qd[base + r * SHD] = f2bf(acc[rt][ct][r]);
            } else if (which == 1) {
                int base = (bh * SS + s0) * SHD + hd;
#pragma unroll
                for (int r = 0; r < 4; ++r)
                    Kd[base + r * SHD] = f2bf(acc[rt][ct][r]);
            } else {
                int base = (bh * SHD + hd) * SS + s0;  // transposed V
                ushort4 pk;
                pk.x = f2bf(acc[rt][ct][0]);
                pk.y = f2bf(acc[rt][ct][1]);
                pk.z = f2bf(acc[rt][ct][2]);
                pk.w = f2bf(acc[rt][ct][3]);
                *reinterpret_cast<ushort4*>(Vtd + base) = pk;  // s0%4==0 -> 8B aligned
            }
        }
    }
}

// ---------------- output projection GEMM (+bias, fp32 out) ----------------
__global__ __launch_bounds__(256) void gemm_out(
    const unsigned short* __restrict__ ctx,
    const unsigned short* __restrict__ wo16,
    const float* __restrict__ wb,
    float* __restrict__ out) {

    __shared__ __align__(16) unsigned short As[128 * 32];
    __shared__ __align__(16) unsigned short Bs[128 * 32];
    const int tid = threadIdx.x;
    const int tileN = blockIdx.x * 128;
    const int tileM = blockIdx.y * 128;

    f32x4 acc[4][4];
    const f32x4 z = {0.f, 0.f, 0.f, 0.f};
#pragma unroll
    for (int i = 0; i < 4; ++i)
#pragma unroll
        for (int j = 0; j < 4; ++j) acc[i][j] = z;

    gemm128_mainloop(ctx, wo16, SD, tileM, tileN, tid, As, Bs, acc);

    const int lane = tid & 63, quad = lane >> 4, col0 = lane & 15;
    const int wr = tid >> 7, wc = (tid >> 6) & 1;

#pragma unroll
    for (int ct = 0; ct < 4; ++ct) {
        int n = tileN + wc * 64 + ct * 16 + col0;
        float bias = wb[n];
#pragma unroll
        for (int rt = 0; rt < 4; ++rt) {
            int m0 = tileM + wr * 64 + rt * 16 + quad * 4;
#pragma unroll
            for (int r = 0; r < 4; ++r)
                out[(size_t)(m0 + r) * SD + n] = acc[rt][ct][r] + bias;
        }
    }
}

// ---------------- flash attention ----------------
// grid (S/128, B*H); block 256 = 4 waves; wave owns 32 q rows (2 row-tiles).
// K tile 64 keys. LDS stride 72 elements (16B-aligned pad, breaks conflicts).
#define LSTR 72
__global__ __launch_bounds__(256) void attn_kernel(
    const unsigned short* __restrict__ Qg,
    const unsigned short* __restrict__ Kg,
    const unsigned short* __restrict__ Vtg,
    unsigned short* __restrict__ ctx) {

    __shared__ __align__(16) unsigned short Ks[64 * LSTR];
    __shared__ __align__(16) unsigned short Vs[64 * LSTR];
    __shared__ __align__(16) unsigned short Ps[4 * 32 * LSTR];

    const int tid = threadIdx.x;
    const int w = tid >> 6;
    const int lane = tid & 63;
    const int quad = lane >> 4;
    const int col0 = lane & 15;
    const int qt = blockIdx.x;
    const int bh = blockIdx.y;
    const int b = bh >> 4;
    const int h = bh & 15;
    const size_t base = (size_t)bh * (SS * SHD);   // per-(b,h) slab
    const int qr0 = qt * 128 + w * 32;

    // Q fragments in registers (A-layout): rows 32, K=64 in two 32-chunks
    bf16x8 aq[2][2];
#pragma unroll
    for (int rt = 0; rt < 2; ++rt)
#pragma unroll
        for (int ks = 0; ks < 2; ++ks) {
            int row = qr0 + rt * 16 + col0;
            aq[rt][ks] = *reinterpret_cast<const bf16x8*>(
                Qg + base + (size_t)row * SHD + ks * 32 + quad * 8);
        }

    float mrow[2][4], lrow[2][4];
    f32x4 Oacc[2][4];
    const f32x4 z = {0.f, 0.f, 0.f, 0.f};
#pragma unroll
    for (int rt = 0; rt < 2; ++rt)
#pragma unroll
        for (int r = 0; r < 4; ++r) { mrow[rt][r] = -3.0e38f; lrow[rt][r] = 0.f; }
#pragma unroll
    for (int rt = 0; rt < 2; ++rt)
#pragma unroll
        for (int ct = 0; ct < 4; ++ct) Oacc[rt][ct] = z;

    const int nkt = 2 * qt + 2;
    for (int kt = 0; kt < nkt; ++kt) {
        __syncthreads();
        // stage K tile [64 keys][64 hd] and Vt tile [64 hd][64 keys]
#pragma unroll
        for (int it = 0; it < 2; ++it) {
            int slot = it * 256 + tid;
            int row = slot >> 3;
            int ch = (slot & 7) * 8;
            bf16x8 kv = *reinterpret_cast<const bf16x8*>(
                Kg + base + (size_t)(kt * 64 + row) * SHD + ch);
            *reinterpret_cast<bf16x8*>(&Ks[row * LSTR + ch]) = kv;
            bf16x8 vv = *reinterpret_cast<const bf16x8*>(
                Vtg + base + (size_t)row * SS + kt * 64 + ch);
            *reinterpret_cast<bf16x8*>(&Vs[row * LSTR + ch]) = vv;
        }
        __syncthreads();

        if (kt * 64 <= qr0 + 31) {   // skip fully-masked tiles for this wave
            // ---- scores = Q K^T ----
            f32x4 sc[2][4];
#pragma unroll
            for (int rt = 0; rt < 2; ++rt)
#pragma unroll
                for (int ct = 0; ct < 4; ++ct) sc[rt][ct] = z;
#pragma unroll
            for (int ks = 0; ks < 2; ++ks)
#pragma unroll
                for (int ct = 0; ct < 4; ++ct) {
                    bf16x8 bk = *reinterpret_cast<const bf16x8*>(
                        &Ks[(ct * 16 + col0) * LSTR + ks * 32 + quad * 8]);
#pragma unroll
                    for (int rt = 0; rt < 2; ++rt)
                        sc[rt][ct] = __builtin_amdgcn_mfma_f32_16x16x32_bf16(
                            aq[rt][ks], bk, sc[rt][ct], 0, 0, 0);
                }

            // ---- scale + causal mask ----
            const bool need_mask = (kt * 64 + 63) > qr0;
#pragma unroll
            for (int rt = 0; rt < 2; ++rt)
#pragma unroll
                for (int ct = 0; ct < 4; ++ct)
#pragma unroll
                    for (int r = 0; r < 4; ++r) {
                        float v = sc[rt][ct][r] * 0.125f;
                        if (need_mask) {
                            int key = kt * 64 + ct * 16 + col0;
                            int qq = qr0 + rt * 16 + quad * 4 + r;
                            if (key > qq) v = -3.0e38f;
                        }
                        sc[rt][ct][r] = v;
                    }

            // ---- online softmax ----
            float alpha[2][4];
#pragma unroll
            for (int rt = 0; rt < 2; ++rt)
#pragma unroll
                for (int r = 0; r < 4; ++r) {
                    float v = fmaxf(fmaxf(sc[rt][0][r], sc[rt][1][r]),
                                    fmaxf(sc[rt][2][r], sc[rt][3][r]));
                    v = fmaxf(v, __shfl_xor(v, 1));
                    v = fmaxf(v, __shfl_xor(v, 2));
                    v = fmaxf(v, __shfl_xor(v, 4));
                    v = fmaxf(v, __shfl_xor(v, 8));
                    float mn = fmaxf(mrow[rt][r], v);
                    float a = exp2f((mrow[rt][r] - mn) * 1.44269504f);
                    mrow[rt][r] = mn;
                    lrow[rt][r] *= a;
                    alpha[rt][r] = a;
                }
#pragma unroll
            for (int rt = 0; rt < 2; ++rt)
#pragma unroll
                for (int ct = 0; ct < 4; ++ct)
#pragma unroll
                    for (int r = 0; r < 4; ++r)
                        sc[rt][ct][r] = exp2f((sc[rt][ct][r] - mrow[rt][r]) * 1.44269504f);
#pragma unroll
            for (int rt = 0; rt < 2; ++rt)
#pragma unroll
                for (int r = 0; r < 4; ++r) {
                    float s = ((sc[rt][0][r] + sc[rt][1][r]) +
                               (sc[rt][2][r] + sc[rt][3][r]));
                    s += __shfl_xor(s, 1);
                    s += __shfl_xor(s, 2);
                    s += __shfl_xor(s, 4);
                    s += __shfl_xor(s, 8);
                    lrow[rt][r] += s;
                }
            // rescale O
#pragma unroll
            for (int rt = 0; rt < 2; ++rt)
#pragma unroll
                for (int ct = 0; ct < 4; ++ct)
#pragma unroll
                    for (int r = 0; r < 4; ++r)
                        Oacc[rt][ct][r] *= alpha[rt][r];

            // ---- P -> LDS (C-layout to A-layout round trip) ----
#pragma unroll
            for (int rt = 0; rt < 2; ++rt)
#pragma unroll
                for (int ct = 0; ct < 4; ++ct)
#pragma unroll
                    for (int r = 0; r < 4; ++r)
                        Ps[(w * 32 + rt * 16 + quad * 4 + r) * LSTR + ct * 16 + col0] =
                            f2bf(sc[rt][ct][r]);

            // ---- O += P V ----
#pragma unroll
            for (int ks = 0; ks < 2; ++ks) {
                bf16x8 ap[2];
#pragma unroll
                for (int rt = 0; rt < 2; ++rt)
                    ap[rt] = *reinterpret_cast<const bf16x8*>(
                        &Ps[(w * 32 + rt * 16 + col0) * LSTR + ks * 32 + quad * 8]);
#pragma unroll
                for (int ct = 0; ct < 4; ++ct) {
                    bf16x8 bv = *reinterpret_cast<const bf16x8*>(
                        &Vs[(ct * 16 + col0) * LSTR + ks * 32 + quad * 8]);
#pragma unroll
                    for (int rt = 0; rt < 2; ++rt)
                        Oacc[rt][ct] = __builtin_amdgcn_mfma_f32_16x16x32_bf16(
                            ap[rt], bv, Oacc[rt][ct], 0, 0, 0);
                }
            }
        }
    }

    // ---- epilogue: ctx[b][s][h*64+hd] bf16 ----
#pragma unroll
    for (int rt = 0; rt < 2; ++rt)
#pragma unroll
        for (int r = 0; r < 4; ++r) {
            float inv = 1.0f / lrow[rt][r];
            int qq = qr0 + rt * 16 + quad * 4 + r;
#pragma unroll
            for (int ct = 0; ct < 4; ++ct) {
                size_t addr = ((size_t)b * SS + qq) * SD + h * SHD + ct * 16 + col0;
                ctx[addr] = f2bf(Oacc[rt][ct][r] * inv);
            }
        }
}

// ---------------- launcher ----------------
// ws layout (bytes):
//  xb    @ 0          16,777,216
//  wqkv  @ 16777216    6,291,456
//  q     @ 23068672   16,777,216
//  k     @ 39845888   16,777,216
//  vt    @ 56623104   16,777,216
//  ctx   @ 73400320   16,777,216
//  wo16  @ 90177536    2,097,152   total 92,274,688
extern "C" void kernel_launch(void* const* d_in, const int* in_sizes, int n_in,
                              void* d_out, int out_size, void* d_ws, size_t ws_size,
                              hipStream_t stream) {
    const float* x  = (const float*)d_in[0];
    const float* wq = (const float*)d_in[1];
    const float* wk = (const float*)d_in[2];
    const float* wv = (const float*)d_in[3];
    const float* wo = (const float*)d_in[4];
    const float* wb = (const float*)d_in[5];
    float* out = (float*)d_out;

    char* ws = (char*)d_ws;
    unsigned short* xb   = (unsigned short*)(ws + 0);
    unsigned short* wqkv = (unsigned short*)(ws + 16777216);
    unsigned short* q    = (unsigned short*)(ws + 23068672);
    unsigned short* k    = (unsigned short*)(ws + 39845888);
    unsigned short* vt   = (unsigned short*)(ws + 56623104);
    unsigned short* ctx  = (unsigned short*)(ws + 73400320);
    unsigned short* wo16 = (unsigned short*)(ws + 90177536);

    // casts
    cast_kernel<<<(SM * SD / 4 + 255) / 256, 256, 0, stream>>>(x, xb, SM * SD / 4);
    cast_kernel<<<(SD * SD / 4 + 255) / 256, 256, 0, stream>>>(wq, wqkv, SD * SD / 4);
    cast_kernel<<<(SD * SD / 4 + 255) / 256, 256, 0, stream>>>(wk, wqkv + SD * SD, SD * SD / 4);
    cast_kernel<<<(SD * SD / 4 + 255) / 256, 256, 0, stream>>>(wv, wqkv + 2 * SD * SD, SD * SD / 4);
    cast_kernel<<<(SD * SD / 4 + 255) / 256, 256, 0, stream>>>(wo, wo16, SD * SD / 4);

    // QKV projection: M=8192, N=3072
    gemm_qkv<<<dim3(3 * SD / 128, SM / 128), 256, 0, stream>>>(xb, wqkv, q, k, vt);

    // attention: grid (S/128, B*H)
    attn_kernel<<<dim3(SS / 128, SB * SH), 256, 0, stream>>>(q, k, vt, ctx);

    // output projection: M=8192, N=1024, +bias, fp32 out
    gemm_out<<<dim3(SD / 128, SM / 128), 256, 0, stream>>>(ctx, wo16, wb, out);
}